// Round 3
// baseline (176.584 us; speedup 1.0000x reference)
//
#include <hip/hip_runtime.h>
#include <stdint.h>

// Problem constants (from reference: shape (32,1,512,512) fp32)
#define BATCH 32
#define H 512
#define W 512
#define N_TOT (BATCH * H * W)          // 8388608
#define BAND 16                        // output rows per block
#define STEPS (BAND / 2)               // 8 (2 rows per step)
#define NBLOCKS (BATCH * (H / BAND))   // 1024
#define RING 6                         // LDS ring slots (row-triples)
#define ROWF 512                       // floats per staged row (full width)
#define TRIPF (3 * ROWF)               // 1536 floats per row-triple (A,B,F)
#define LDSF (RING * TRIPF)            // 9216 floats = 36 KB ring

// R3: LDS-staged streaming rewrite. Old register-ring version capped at
// ~2.9 TB/s effective (40.9 us, VALUBusy 18%, HBM 19%): each wave held only
// one row-triple (~3 KB) in flight and serialized on per-iteration waitcnt.
// New structure: block = 4 waves owns a 16-row full-width band; row-triples
// (A,B,F rows, 6 KB) stream into a 6-slot LDS ring via
// __builtin_amdgcn_global_load_lds (16B/lane granules, 12 KB/block in
// flight ~= 5x BDP per CU across 4 blocks/CU). Compute: waves (d=ty>>1,
// h=ty&1) produce rows r0+2p+d, cols h*256..+255, 4 px/lane, windows read
// from LDS with register carry of the y+1 window into next step's y-1.
// Per-step: stage-next -> ds_read+compute -> __syncthreads (drains vmcnt).
// OOB rows (y=-1, y=512) are zero-filled in LDS at stage time = reference
// zero padding; x-boundary handled by masking the two edge lanes.

#define GAS(p) ((__attribute__((address_space(1))) void*)(p))
#define LAS(p) ((__attribute__((address_space(3))) void*)(p))

template <bool USE_PARTIALS>
__global__ __launch_bounds__(256)
void fusion_loss_kernel(const float* __restrict__ A,
                        const float* __restrict__ B,
                        const float* __restrict__ F,
                        const int* __restrict__ scheme_arr,
                        float* __restrict__ sink)   // partials[] or out scalar
{
    __shared__ float sh[LDSF];
    __shared__ float red[4];

    const int t    = threadIdx.x;
    const int lane = t & 63;
    const int ty   = t >> 6;            // wave id in block (0..3)
    const int d    = ty >> 1;           // row parity within pair (0,1)
    const int h    = ty & 1;            // column half (0 = cols 0-255)
    const int blk  = blockIdx.x;
    const int b    = blk >> 5;          // batch (32 bands per image)
    const int band = blk & 31;
    const int r0   = band << 4;         // first output row of the band
    const int base = b * (H * W);
    const int scheme = scheme_arr[b];

    const bool edgeL = (h == 0) && (lane == 0);    // col -1 -> zero pad
    const bool edgeR = (h == 1) && (lane == 63);   // col 512 -> zero pad

    // ---- staging: seq s = input row r0-1+s, s in [0,17]; slot = s % RING.
    // Granule g of a triple-pair: trip = g/6, sub = g%6, img = sub>>1,
    // half = sub&1; each wave takes g = ty, ty+4, ... (wave-uniform flow).
    auto stage = [&](int s0, int ng) {
        for (int i = 0; ; ++i) {
            const int g = ty + (i << 2);
            if (g >= ng) break;
            const int trip = g / 6;
            const int sub  = g - 6 * trip;
            const int img  = sub >> 1;
            const int hh   = sub & 1;
            const int s    = s0 + trip;
            const int slot = s % RING;
            const int y    = r0 - 1 + s;
            float* ldst = &sh[slot * TRIPF + img * ROWF + (hh << 8)];
            if ((unsigned)y < (unsigned)H) {
                const float* ip = (img == 0) ? A : (img == 1) ? B : F;
                const float* gsrc = ip + base + y * W + (hh << 8) + (lane << 2);
                __builtin_amdgcn_global_load_lds(GAS(gsrc), LAS(ldst), 16, 0, 0);
            } else {
                // zero padding row (reference's 'same' conv zero pad)
                *reinterpret_cast<float4*>(ldst + (lane << 2)) =
                    make_float4(0.f, 0.f, 0.f, 0.f);
            }
        }
    };

    // ---- window read: w[im][0..5] = lds row cols x0-1 .. x0+4 ----
    auto load_win = [&](float (*w)[6], int seqz) {
        const int slot = seqz % RING;
        const float* srow = &sh[slot * TRIPF];
        const int ci = lane << 2;
#pragma unroll
        for (int im = 0; im < 3; ++im) {
            const float* rowp = srow + im * ROWF + (h << 8);
            const float4 c = *reinterpret_cast<const float4*>(rowp + ci);
            const int li = edgeL ? ci : ci - 1;       // safe in-bounds addr
            const int ri = edgeR ? ci + 3 : ci + 4;
            float l = rowp[li];
            float r = rowp[ri];
            if (edgeL) l = 0.f;
            if (edgeR) r = 0.f;
            w[im][0] = l;   w[im][1] = c.x; w[im][2] = c.y;
            w[im][3] = c.z; w[im][4] = c.w; w[im][5] = r;
        }
    };

    // prologue: stage seqs 0..3 (rows r0-1..r0+2), 24 granules / 6 per wave
    stage(0, 24);
    __syncthreads();

    float wm[3][6], wc[3][6], wp[3][6];
    load_win(wm, d);                       // sm for step 0 (row r0+d-1)

    float acc = 0.f;

    for (int p = 0; p < STEPS; ++p) {
        // issue next pair's staging first (seqs 2p+4, 2p+5 -> slots of the
        // pair retired two steps ago; barrier at end of p-1 made them dead)
        if (p < STEPS - 1) stage(2 * p + 4, 12);

        load_win(wc, d + 2 * p + 1);       // row y   = r0+2p+d
        load_win(wp, d + 2 * p + 2);       // row y+1

        float sobM[4];
#pragma unroll
        for (int im = 0; im < 3; ++im) {
            float gx[4], gy[4];
#pragma unroll
            for (int j = 0; j < 4; ++j) {
                gx[j] = (wm[im][j + 2] - wm[im][j])
                      + 2.f * (wc[im][j + 2] - wc[im][j])
                      + (wp[im][j + 2] - wp[im][j]);
                gy[j] = (wm[im][j] + 2.f * wm[im][j + 1] + wm[im][j + 2])
                      - (wp[im][j] + 2.f * wp[im][j + 1] + wp[im][j + 2]);
            }
#pragma unroll
            for (int j = 0; j < 4; ++j) {
                const float sob = fabsf(gx[j]) + fabsf(gy[j]);
                if (im == 0)      sobM[j] = sob;
                else if (im == 1) sobM[j] = fmaxf(sobM[j], sob);
                else              acc += fabsf(sob - sobM[j]);
            }
        }

        // l_loss on the center row's 4 px (wc[...][1..4] = cols x0..x0+3)
#pragma unroll
        for (int j = 0; j < 4; ++j) {
            const float av = wc[0][j + 1];
            const float bv = wc[1][j + 1];
            const float fv = wc[2][j + 1];
            const float ab = (scheme == 0) ? 0.5f * (av + bv)
                           : (scheme == 1) ? fmaxf(av, bv)
                           : 0.f;
            acc += fabsf(ab - fv);
        }

        // carry: this step's y+1 window is next step's y-1 window
#pragma unroll
        for (int im = 0; im < 3; ++im)
#pragma unroll
            for (int k = 0; k < 6; ++k)
                wm[im][k] = wp[im][k];

        // drains vmcnt(0)+lgkmcnt(0) (staging landed) and syncs slot reuse
        __syncthreads();
    }

    // ---- reduction: 64-lane shuffle, cross-wave via LDS, one plain store
    // per block to a distinct workspace slot (parallel drain, no atomics).
#pragma unroll
    for (int off = 32; off > 0; off >>= 1)
        acc += __shfl_down(acc, off, 64);
    if (lane == 0) red[ty] = acc;
    __syncthreads();
    if (t == 0) {
        const float s = red[0] + red[1] + red[2] + red[3];
        if (USE_PARTIALS)
            sink[blockIdx.x] = s;
        else
            atomicAdd(sink, s * (1.0f / (float)N_TOT)); // fallback path
    }
}

// 1-block finish: sum NBLOCKS partials (256 threads x 1 float4 = 1024
// floats), scale by 1/N, write the scalar. Kernel boundary on the stream
// guarantees visibility of kernel1's plain stores.
__global__ __launch_bounds__(256)
void fusion_finish(const float* __restrict__ partials, float* __restrict__ out)
{
    __shared__ float red[4];
    const int t    = threadIdx.x;
    const int lane = t & 63;
    const int ty   = t >> 6;

    const float4 p = reinterpret_cast<const float4*>(partials)[t];
    float v = (p.x + p.y) + (p.z + p.w);
#pragma unroll
    for (int off = 32; off > 0; off >>= 1)
        v += __shfl_down(v, off, 64);
    if (lane == 0) red[ty] = v;
    __syncthreads();
    if (t == 0)
        out[0] = (red[0] + red[1] + red[2] + red[3]) * (1.0f / (float)N_TOT);
}

extern "C" void kernel_launch(void* const* d_in, const int* in_sizes, int n_in,
                              void* d_out, int out_size, void* d_ws, size_t ws_size,
                              hipStream_t stream)
{
    const float* A = (const float*)d_in[0];
    const float* B = (const float*)d_in[1];
    const float* F = (const float*)d_in[2];
    const int* scheme = (const int*)d_in[3];
    float* out = (float*)d_out;

    if (d_ws != nullptr && ws_size >= NBLOCKS * sizeof(float)) {
        float* partials = (float*)d_ws;   // 4 KB, 16B-aligned
        fusion_loss_kernel<true><<<dim3(NBLOCKS), dim3(256), 0, stream>>>(
            A, B, F, scheme, partials);
        fusion_finish<<<dim3(1), dim3(256), 0, stream>>>(partials, out);
    } else {
        // Fallback: atomic path (d_out poisoned -> zero it).
        hipMemsetAsync(out, 0, sizeof(float), stream);
        fusion_loss_kernel<false><<<dim3(NBLOCKS), dim3(256), 0, stream>>>(
            A, B, F, scheme, out);
    }
}

// Round 4
// 153.771 us; speedup vs baseline: 1.1484x; 1.1484x over previous
//
#include <hip/hip_runtime.h>

// Problem constants (from reference: shape (32,1,512,512) fp32)
#define BATCH 32
#define H 512
#define W 512
#define N_TOT (BATCH * H * W)          // 8388608
#define BAND 16                        // output rows per block
#define STEPS 16                       // 1 row per step
#define NBLOCKS (BATCH * (H / BAND))   // 1024
#define RING 4                         // LDS ring slots (row-triples)
#define ROWF 512                       // floats per staged row (full width)
#define TRIPF (3 * ROWF)               // 1536 floats per row-triple (A,B,F)
#define LDSF (RING * TRIPF)            // 6144 floats = 24 KB ring

// R4: spill-proof LDS-ring streaming. R3's 80us regression was scratch
// spill (VGPR 52, WRITE_SIZE 24.6 MB = scratch traffic): window arrays
// passed by pointer into a lambda + non-unrolled step loop -> address-taken
// arrays in scratch. This version: macros only, step loop fully unrolled
// (all ring-slot indices fold to literals -> SROA keeps the 36-float window
// state in registers; carry becomes register renaming). Decomposition:
// block = 256 threads = full 512-px row, 2 px/thread; 1 output row/step.
// LDS reads are ds_read_b64 stride-8B (2-way bank alias = free) + 2 scalar
// halos, killing R3's 2.5M conflicts (b128 stride-16B was 8-way).
// Staging: 6 granules/row-triple via global_load_lds x16B (waves 0,1 carry
// 2 granules, waves 2,3 one); RING=4 gives 2 barriers of write-to-read
// slack; per-step __syncthreads drains vmcnt (2-phase discipline),
// cross-block overlap (4 blocks/CU) hides the drain.

#define GAS(p) ((__attribute__((address_space(1))) void*)(p))
#define LAS(p) ((__attribute__((address_space(3))) void*)(p))

template <bool USE_PARTIALS>
__global__ __launch_bounds__(256)
void fusion_loss_kernel(const float* __restrict__ A,
                        const float* __restrict__ B,
                        const float* __restrict__ F,
                        const int* __restrict__ scheme_arr,
                        float* __restrict__ sink)   // partials[] or out scalar
{
    __shared__ float sh[LDSF];
    __shared__ float red[4];

    const int t    = threadIdx.x;
    const int lane = t & 63;
    const int ty   = t >> 6;            // wave id (0..3)
    const int blk  = blockIdx.x;
    const int b    = blk >> 5;          // batch (32 bands per image)
    const int r0   = (blk & 31) << 4;   // first output row of the band
    const int base = b * (H * W);
    const int scheme = scheme_arr[b];

    // staging granule assignment (wave-uniform):
    //   granule0: wave ty -> image im0 = ty>>1 (A,A,B,B), half hf0 = ty&1
    //   granule1: waves 0,1 -> image F, half = ty
    const int im0 = ty >> 1;
    const int hf0 = ty & 1;
    const float* img0 = (im0 == 0) ? A : B;
    const bool g1 = (ty < 2);
    const int hf1 = ty;                 // valid when g1

    // seq s in [0,17] <-> input row y = r0-1+s; slot = s & 3.
#define STAGE(s_) do {                                                      \
    const int y_ = r0 - 1 + (s_);                                           \
    float* ld_ = sh + ((s_) & 3) * TRIPF;                                   \
    if ((unsigned)y_ < (unsigned)H) {                                       \
        const float* s0p_ = img0 + base + y_ * W + (hf0 << 8) + (lane << 2);\
        __builtin_amdgcn_global_load_lds(GAS(s0p_),                         \
            LAS(ld_ + im0 * ROWF + (hf0 << 8)), 16, 0, 0);                  \
        if (g1) {                                                           \
            const float* s1p_ = F + base + y_ * W + (hf1 << 8) + (lane << 2);\
            __builtin_amdgcn_global_load_lds(GAS(s1p_),                     \
                LAS(ld_ + 2 * ROWF + (hf1 << 8)), 16, 0, 0);                \
        }                                                                   \
    } else {  /* zero padding row = reference 'same' conv zero pad */       \
        reinterpret_cast<float4*>(ld_ + im0 * ROWF + (hf0 << 8))[lane] =    \
            make_float4(0.f, 0.f, 0.f, 0.f);                                \
        if (g1)                                                             \
            reinterpret_cast<float4*>(ld_ + 2 * ROWF + (hf1 << 8))[lane] =  \
                make_float4(0.f, 0.f, 0.f, 0.f);                            \
    }                                                                       \
} while (0)

    // per-thread window geometry: 2 px at cols c0, c0+1
    const int c0 = t << 1;
    const bool eL = (t == 0), eR = (t == 255);
    const int li = eL ? 0   : c0 - 1;   // in-bounds addr, masked below
    const int ri = eR ? 511 : c0 + 2;

    // LOADW: w_[im][0..3] = LDS row (seq s_) cols c0-1, c0, c0+1, c0+2
#define LOADW(w_, s_) do {                                                  \
    const float* lp_ = sh + ((s_) & 3) * TRIPF;                             \
    _Pragma("unroll")                                                       \
    for (int im_ = 0; im_ < 3; ++im_) {                                     \
        const float* rp_ = lp_ + im_ * ROWF;                                \
        const float2 c_ = *reinterpret_cast<const float2*>(rp_ + c0);       \
        float l_ = rp_[li], r_ = rp_[ri];                                   \
        if (eL) l_ = 0.f;                                                   \
        if (eR) r_ = 0.f;                                                   \
        w_[im_][0] = l_;  w_[im_][1] = c_.x;                                \
        w_[im_][2] = c_.y; w_[im_][3] = r_;                                 \
    }                                                                       \
} while (0)

    float wm[3][4], wc[3][4], wp[3][4];
    float acc = 0.f;

#define COMPUTE() do {                                                      \
    float sob0, sob1;                                                       \
    _Pragma("unroll")                                                       \
    for (int im_ = 0; im_ < 3; ++im_) {                                     \
        const float gx0 = (wm[im_][2] - wm[im_][0])                         \
                        + 2.f * (wc[im_][2] - wc[im_][0])                   \
                        + (wp[im_][2] - wp[im_][0]);                        \
        const float gx1 = (wm[im_][3] - wm[im_][1])                         \
                        + 2.f * (wc[im_][3] - wc[im_][1])                   \
                        + (wp[im_][3] - wp[im_][1]);                        \
        const float gy0 = (wm[im_][0] + 2.f * wm[im_][1] + wm[im_][2])      \
                        - (wp[im_][0] + 2.f * wp[im_][1] + wp[im_][2]);     \
        const float gy1 = (wm[im_][1] + 2.f * wm[im_][2] + wm[im_][3])      \
                        - (wp[im_][1] + 2.f * wp[im_][2] + wp[im_][3]);     \
        const float s0_ = fabsf(gx0) + fabsf(gy0);                          \
        const float s1_ = fabsf(gx1) + fabsf(gy1);                          \
        if (im_ == 0)      { sob0 = s0_; sob1 = s1_; }                      \
        else if (im_ == 1) { sob0 = fmaxf(sob0, s0_);                       \
                             sob1 = fmaxf(sob1, s1_); }                     \
        else               { acc += fabsf(s0_ - sob0) + fabsf(s1_ - sob1); }\
    }                                                                       \
    {   const float a0 = wc[0][1], a1 = wc[0][2];                           \
        const float b0 = wc[1][1], b1 = wc[1][2];                           \
        const float f0 = wc[2][1], f1 = wc[2][2];                           \
        const float ab0 = (scheme == 0) ? 0.5f * (a0 + b0)                  \
                        : (scheme == 1) ? fmaxf(a0, b0) : 0.f;              \
        const float ab1 = (scheme == 0) ? 0.5f * (a1 + b1)                  \
                        : (scheme == 1) ? fmaxf(a1, b1) : 0.f;              \
        acc += fabsf(ab0 - f0) + fabsf(ab1 - f1);                           \
    }                                                                       \
} while (0)

#define CARRY() do {                                                        \
    _Pragma("unroll")                                                       \
    for (int im_ = 0; im_ < 3; ++im_) {                                     \
        _Pragma("unroll")                                                   \
        for (int j_ = 0; j_ < 4; ++j_) {                                    \
            wm[im_][j_] = wc[im_][j_];                                      \
            wc[im_][j_] = wp[im_][j_];                                      \
        }                                                                   \
    }                                                                       \
} while (0)

    // prologue: fill the ring (seqs 0..3 = rows r0-1..r0+2)
    STAGE(0); STAGE(1); STAGE(2); STAGE(3);
    __syncthreads();
    LOADW(wm, 0);                       // row r0-1
    LOADW(wc, 1);                       // row r0
    __syncthreads();  // all waves' prologue ds_reads done before slot reuse

    // step p: compute row r0+p (wm/wc carried, wp = seq p+2);
    // stage seq p+4 into the slot whose data was consumed at step p-2.
#pragma unroll
    for (int p = 0; p < STEPS; ++p) {
        if (p + 4 <= 17) STAGE(p + 4);
        LOADW(wp, p + 2);
        COMPUTE();
        CARRY();
        __syncthreads();   // drains vmcnt (staged triple landed) + slot sync
    }

    // ---- reduction: 64-lane shuffle, cross-wave via LDS, one plain store
    // per block to a distinct workspace slot (parallel drain, no atomics).
#pragma unroll
    for (int off = 32; off > 0; off >>= 1)
        acc += __shfl_down(acc, off, 64);
    if (lane == 0) red[ty] = acc;
    __syncthreads();
    if (t == 0) {
        const float s = red[0] + red[1] + red[2] + red[3];
        if (USE_PARTIALS)
            sink[blockIdx.x] = s;
        else
            atomicAdd(sink, s * (1.0f / (float)N_TOT)); // fallback path
    }
#undef STAGE
#undef LOADW
#undef COMPUTE
#undef CARRY
}

// 1-block finish: sum NBLOCKS partials (256 threads x 1 float4 = 1024
// floats), scale by 1/N, write the scalar. Kernel boundary on the stream
// guarantees visibility of kernel1's plain stores.
__global__ __launch_bounds__(256)
void fusion_finish(const float* __restrict__ partials, float* __restrict__ out)
{
    __shared__ float red[4];
    const int t    = threadIdx.x;
    const int lane = t & 63;
    const int ty   = t >> 6;

    const float4 p = reinterpret_cast<const float4*>(partials)[t];
    float v = (p.x + p.y) + (p.z + p.w);
#pragma unroll
    for (int off = 32; off > 0; off >>= 1)
        v += __shfl_down(v, off, 64);
    if (lane == 0) red[ty] = v;
    __syncthreads();
    if (t == 0)
        out[0] = (red[0] + red[1] + red[2] + red[3]) * (1.0f / (float)N_TOT);
}

extern "C" void kernel_launch(void* const* d_in, const int* in_sizes, int n_in,
                              void* d_out, int out_size, void* d_ws, size_t ws_size,
                              hipStream_t stream)
{
    const float* A = (const float*)d_in[0];
    const float* B = (const float*)d_in[1];
    const float* F = (const float*)d_in[2];
    const int* scheme = (const int*)d_in[3];
    float* out = (float*)d_out;

    if (d_ws != nullptr && ws_size >= NBLOCKS * sizeof(float)) {
        float* partials = (float*)d_ws;   // 4 KB, 16B-aligned
        fusion_loss_kernel<true><<<dim3(NBLOCKS), dim3(256), 0, stream>>>(
            A, B, F, scheme, partials);
        fusion_finish<<<dim3(1), dim3(256), 0, stream>>>(partials, out);
    } else {
        // Fallback: atomic path (d_out poisoned -> zero it).
        hipMemsetAsync(out, 0, sizeof(float), stream);
        fusion_loss_kernel<false><<<dim3(NBLOCKS), dim3(256), 0, stream>>>(
            A, B, F, scheme, out);
    }
}

// Round 5
// 121.734 us; speedup vs baseline: 1.4506x; 1.2632x over previous
//
#include <hip/hip_runtime.h>

// Problem constants (from reference: shape (32,1,512,512) fp32)
#define BATCH 32
#define H 512
#define W 512
#define N_TOT (BATCH * H * W)          // 8388608
#define ROWS_TOTAL (BATCH * H)         // 16384
#define NBLOCKS (ROWS_TOTAL / 4)       // 4096 blocks x 4 waves = 1 row/wave
#define WS_FLOATS NBLOCKS

// R5: barrier-free full-row waves, max MLP. R0 (reg-ring) and R3/R4
// (LDS-ring) both throttled memory-level parallelism through loop-carried
// state / per-step vmcnt(0) barrier drains (R4: VGPR 164 -> 2 waves/SIMD,
// occupancy 10%, 58 us). The op is a 3x3 stencil over ~L3-resident inputs;
// floors: HBM ~9.5 us (FETCH ~60 MB), L1-transactions ~7.7 us, VALU ~5 us.
// This version: wave = one full 512-px row, 8 px/lane. 18 independent
// float4 loads per thread issued up front (18 KB in flight/wave), column
// halos via __shfl (lane edges == image edges == zero-pad, so NO halo
// loads, no cross-wave traffic), zero __syncthreads in the hot path.
// Vertical 3x re-reads hit L2/L3; XCD-bijective swizzle (4096%8==0) gives
// each XCD 2048 contiguous rows so halo re-reads are same-XCD L2 hits.
// __launch_bounds__(256,4) caps VGPR at 128 (occupancy steps at 64/128/256
// per m69; R4's 164 VGPR fell to 2 waves/SIMD). NOTE: harness dur_us
// includes ~82 us of 268 MB fillBufferAligned re-poison dispatches; only
// the kernel's own time is ours to optimize.

template <bool USE_PARTIALS>
__global__ __launch_bounds__(256, 4)
void fusion_loss_kernel(const float* __restrict__ A,
                        const float* __restrict__ B,
                        const float* __restrict__ F,
                        const int* __restrict__ scheme_arr,
                        float* __restrict__ sink)   // partials[] or out scalar
{
    __shared__ float red[4];

    const int t    = threadIdx.x;
    const int lane = t & 63;
    const int ty   = t >> 6;

    // XCD-bijective swizzle: hw assigns xcd ~ blockIdx%8; remap so each XCD
    // owns NBLOCKS/8 = 512 consecutive logical blocks (2048 contiguous rows).
    const int bid = blockIdx.x;
    const int lb  = (bid & 7) * (NBLOCKS / 8) + (bid >> 3);

    const int gy  = (lb << 2) | ty;       // global row 0..16383 (1 row/wave)
    const int b   = gy >> 9;              // batch (rows 512-aligned, blocks
    const int y   = gy & (H - 1);         //  4-row aligned -> no batch split)
    const int x0  = lane << 3;            // 8 px per lane
    const int scheme = scheme_arr[b];

    const int off = gy * W + x0;          // gy*W == (b*H + y)*W
    const bool vm = (y > 0);
    const bool vp = (y < H - 1);

    // u0 = cols x0..x0+3, u1 = cols x0+4..x0+7; rows r: 0=y-1, 1=y, 2=y+1
    float4 u0[3][3], u1[3][3];
    {
        const float* ptr[3] = {A + off, B + off, F + off};
#pragma unroll
        for (int im = 0; im < 3; ++im) {
            const float* p = ptr[im];
            u0[im][1] = *reinterpret_cast<const float4*>(p);
            u1[im][1] = *reinterpret_cast<const float4*>(p + 4);
            if (vm) {   // wave-uniform branch
                u0[im][0] = *reinterpret_cast<const float4*>(p - W);
                u1[im][0] = *reinterpret_cast<const float4*>(p - W + 4);
            } else {    // reference 'same' conv zero padding
                u0[im][0] = make_float4(0.f, 0.f, 0.f, 0.f);
                u1[im][0] = make_float4(0.f, 0.f, 0.f, 0.f);
            }
            if (vp) {
                u0[im][2] = *reinterpret_cast<const float4*>(p + W);
                u1[im][2] = *reinterpret_cast<const float4*>(p + W + 4);
            } else {
                u0[im][2] = make_float4(0.f, 0.f, 0.f, 0.f);
                u1[im][2] = make_float4(0.f, 0.f, 0.f, 0.f);
            }
        }
    }

    float acc = 0.f;

    // ---- l_loss on this row's 8 px (center rows of A,B,F) ----
#pragma unroll
    for (int hh = 0; hh < 2; ++hh) {
        const float4 a4 = hh ? u1[0][1] : u0[0][1];
        const float4 b4 = hh ? u1[1][1] : u0[1][1];
        const float4 f4 = hh ? u1[2][1] : u0[2][1];
        const float av[4] = {a4.x, a4.y, a4.z, a4.w};
        const float bv[4] = {b4.x, b4.y, b4.z, b4.w};
        const float fv[4] = {f4.x, f4.y, f4.z, f4.w};
#pragma unroll
        for (int j = 0; j < 4; ++j) {
            const float ab = (scheme == 0) ? 0.5f * (av[j] + bv[j])
                           : (scheme == 1) ? fmaxf(av[j], bv[j])
                           : 0.f;
            acc += fabsf(ab - fv[j]);
        }
    }

    // ---- sobel: per image, 10-wide windows for 3 rows, 8 outputs ----
    float sobM[8];
#pragma unroll
    for (int im = 0; im < 3; ++im) {
        float v[3][10];
#pragma unroll
        for (int r = 0; r < 3; ++r) {
            const float4 a = u0[im][r];
            const float4 c = u1[im][r];
            // col x0-1 = lane-1's c.w; col x0+8 = lane+1's a.x.
            // Lane 0 / lane 63 edges are image edges -> zero pad.
            float lN = __shfl_up(c.w, 1, 64);
            float rN = __shfl_down(a.x, 1, 64);
            if (lane == 0)  lN = 0.f;
            if (lane == 63) rN = 0.f;
            v[r][0] = lN;
            v[r][1] = a.x; v[r][2] = a.y; v[r][3] = a.z; v[r][4] = a.w;
            v[r][5] = c.x; v[r][6] = c.y; v[r][7] = c.z; v[r][8] = c.w;
            v[r][9] = rN;
        }
#pragma unroll
        for (int j = 0; j < 8; ++j) {
            const float gx = (v[0][j + 2] - v[0][j])
                           + 2.f * (v[1][j + 2] - v[1][j])
                           + (v[2][j + 2] - v[2][j]);
            const float gyv = (v[0][j] + 2.f * v[0][j + 1] + v[0][j + 2])
                            - (v[2][j] + 2.f * v[2][j + 1] + v[2][j + 2]);
            const float sob = fabsf(gx) + fabsf(gyv);
            if (im == 0)      sobM[j] = sob;
            else if (im == 1) sobM[j] = fmaxf(sobM[j], sob);
            else              acc += fabsf(sob - sobM[j]);
        }
    }

    // ---- reduction: 64-lane shuffle, cross-wave via LDS, one plain store
    // per block to a distinct workspace slot (parallel drain, no atomics).
#pragma unroll
    for (int offp = 32; offp > 0; offp >>= 1)
        acc += __shfl_down(acc, offp, 64);
    if (lane == 0) red[ty] = acc;
    __syncthreads();
    if (t == 0) {
        const float s = red[0] + red[1] + red[2] + red[3];
        if (USE_PARTIALS)
            sink[bid] = s;
        else
            atomicAdd(sink, s * (1.0f / (float)N_TOT)); // fallback path
    }
}

// 1-block finish: sum NBLOCKS=4096 partials (256 threads x 4 float4),
// scale by 1/N, write the scalar. Kernel boundary on the stream guarantees
// visibility of kernel1's plain stores.
__global__ __launch_bounds__(256)
void fusion_finish(const float* __restrict__ partials, float* __restrict__ out)
{
    __shared__ float red[4];
    const int t    = threadIdx.x;
    const int lane = t & 63;
    const int ty   = t >> 6;

    float s = 0.f;
#pragma unroll
    for (int k = 0; k < 4; ++k) {
        const float4 p = reinterpret_cast<const float4*>(partials)[t + 256 * k];
        s += (p.x + p.y) + (p.z + p.w);
    }
#pragma unroll
    for (int off = 32; off > 0; off >>= 1)
        s += __shfl_down(s, off, 64);
    if (lane == 0) red[ty] = s;
    __syncthreads();
    if (t == 0)
        out[0] = (red[0] + red[1] + red[2] + red[3]) * (1.0f / (float)N_TOT);
}

extern "C" void kernel_launch(void* const* d_in, const int* in_sizes, int n_in,
                              void* d_out, int out_size, void* d_ws, size_t ws_size,
                              hipStream_t stream)
{
    const float* A = (const float*)d_in[0];
    const float* B = (const float*)d_in[1];
    const float* F = (const float*)d_in[2];
    const int* scheme = (const int*)d_in[3];
    float* out = (float*)d_out;

    if (d_ws != nullptr && ws_size >= WS_FLOATS * sizeof(float)) {
        float* partials = (float*)d_ws;   // 16 KB, 16B-aligned
        fusion_loss_kernel<true><<<dim3(NBLOCKS), dim3(256), 0, stream>>>(
            A, B, F, scheme, partials);
        fusion_finish<<<dim3(1), dim3(256), 0, stream>>>(partials, out);
    } else {
        // Fallback: atomic path (d_out poisoned -> zero it).
        hipMemsetAsync(out, 0, sizeof(float), stream);
        fusion_loss_kernel<false><<<dim3(NBLOCKS), dim3(256), 0, stream>>>(
            A, B, F, scheme, out);
    }
}